// Round 1
// baseline (23575.836 us; speedup 1.0000x reference)
//
#include <hip/hip_runtime.h>
#include <hip/hip_cooperative_groups.h>

namespace cg = cooperative_groups;

constexpr int B_ = 64, I_ = 256, H_ = 512, T_ = 512;
constexpr int BH_ = B_ * H_;

__device__ __forceinline__ float sigm(float v) { return 1.0f / (1.0f + __expf(-v)); }

__global__ __launch_bounds__(512, 1)
void lstm_fused(const float* __restrict__ x,
                const float* __restrict__ Wih,
                const float* __restrict__ Whh,
                const float* __restrict__ bih,
                const float* __restrict__ bhh,
                const float* __restrict__ h0,
                const float* __restrict__ c0,
                float* __restrict__ out,
                float* __restrict__ hbuf)
{
    // LDS: pad rows so the 8 b-rows land in distinct 4-bank groups (stride%32 == 4)
    __shared__ float xs[8][I_ + 4];     // x column t for 8 batches
    __shared__ float hs[8][H_ + 4];     // h for 8 batches
    __shared__ float red[4][4][129];    // [kquarter][gate][pair] partial sums

    const int tid  = threadIdx.x;
    const int wave = tid >> 6;
    const int lane = tid & 63;
    const int kq   = wave >> 1;                 // k-quarter 0..3 (uniform per wave)
    const int p    = ((wave & 1) << 6) | lane;  // pair index 0..127
    const int bl   = p & 7;                     // local batch 0..7
    const int jl   = p >> 3;                    // local j 0..15

    const int blk = blockIdx.x;
    const int bt  = blk >> 5;                                   // b-tile 0..7
    const int jt  = ((blk & 7) << 2) | ((blk >> 3) & 3);        // j-tile 0..31, XCD-clustered (blk%8 = XCD)
    const int b0  = bt << 3;
    const int b   = b0 + bl;
    const int j   = (jt << 4) + jl;

    // per-(b,j) constants
    float bias[4];
#pragma unroll
    for (int g = 0; g < 4; ++g) bias[g] = bih[g * H_ + j] + bhh[g * H_ + j];

    float c = c0[b * H_ + j];   // cell state lives in a register all 512 steps (used by waves 0-1)

    // K partition over float4 units: x-part has 64, h-part has 128; 48 each
    // kq0: x[0,48) | kq1: x[48,64)+h[0,32) | kq2: h[32,80) | kq3: h[80,128)
    const int nxA[4] = {48, 16, 0, 0};
    const int xoA[4] = {0, 48, 0, 0};
    const int nhA[4] = {0, 32, 48, 48};
    const int hoA[4] = {0, 0, 32, 80};
    const int nx = nxA[kq], xo = xoA[kq], nh = nhA[kq], ho = hoA[kq];

    const float4* wX[4];
    const float4* wH[4];
#pragma unroll
    for (int g = 0; g < 4; ++g) {
        wX[g] = (const float4*)(Wih + (size_t)(g * H_ + j) * I_) + xo;
        wH[g] = (const float4*)(Whh + (size_t)(g * H_ + j) * H_) + ho;
    }
    const float4* actX = (const float4*)(&xs[bl][0]) + xo;
    const float4* actH = (const float4*)(&hs[bl][0]) + ho;

    float* enc = out + BH_;   // encoded (B,H,T) after the (1,B,H) final-h block
    cg::grid_group grid = cg::this_grid();

    for (int t = 0; t < T_; ++t) {
        // ---- stage x(:, :, t) for our 8 batches (strided column reads, cache-served) ----
#pragma unroll
        for (int r = 0; r < 4; ++r) {
            int flat = tid + (r << 9);          // 0..2047
            int bb = flat >> 8, ii = flat & 255;
            xs[bb][ii] = x[(size_t)((b0 + bb) * I_ + ii) * T_ + t];
        }
        // ---- stage h (coalesced float4) ----
        const float* hsrc = t ? (hbuf + ((t - 1) & 1) * BH_) : h0;
#pragma unroll
        for (int r = 0; r < 2; ++r) {
            int flat = tid + (r << 9);          // 0..1023 float4s
            int bb = flat >> 7, k4 = flat & 127;
            float4 v = ((const float4*)(hsrc + (size_t)(b0 + bb) * H_))[k4];
            *(float4*)(&hs[bb][k4 << 2]) = v;
        }
        __syncthreads();

        // ---- 4 gate dot-products over this thread's K slice ----
        float4 a0 = make_float4(0.f,0.f,0.f,0.f), a1 = a0, a2 = a0, a3 = a0;
#pragma unroll 4
        for (int k = 0; k < nx; ++k) {
            float4 a = actX[k];
            float4 w0 = wX[0][k], w1 = wX[1][k], w2 = wX[2][k], w3 = wX[3][k];
            a0.x += a.x*w0.x; a0.y += a.y*w0.y; a0.z += a.z*w0.z; a0.w += a.w*w0.w;
            a1.x += a.x*w1.x; a1.y += a.y*w1.y; a1.z += a.z*w1.z; a1.w += a.w*w1.w;
            a2.x += a.x*w2.x; a2.y += a.y*w2.y; a2.z += a.z*w2.z; a2.w += a.w*w2.w;
            a3.x += a.x*w3.x; a3.y += a.y*w3.y; a3.z += a.z*w3.z; a3.w += a.w*w3.w;
        }
#pragma unroll 4
        for (int k = 0; k < nh; ++k) {
            float4 a = actH[k];
            float4 w0 = wH[0][k], w1 = wH[1][k], w2 = wH[2][k], w3 = wH[3][k];
            a0.x += a.x*w0.x; a0.y += a.y*w0.y; a0.z += a.z*w0.z; a0.w += a.w*w0.w;
            a1.x += a.x*w1.x; a1.y += a.y*w1.y; a1.z += a.z*w1.z; a1.w += a.w*w1.w;
            a2.x += a.x*w2.x; a2.y += a.y*w2.y; a2.z += a.z*w2.z; a2.w += a.w*w2.w;
            a3.x += a.x*w3.x; a3.y += a.y*w3.y; a3.z += a.z*w3.z; a3.w += a.w*w3.w;
        }

        red[kq][0][p] = a0.x + a0.y + a0.z + a0.w;
        red[kq][1][p] = a1.x + a1.y + a1.z + a1.w;
        red[kq][2][p] = a2.x + a2.y + a2.z + a2.w;
        red[kq][3][p] = a3.x + a3.y + a3.z + a3.w;
        __syncthreads();

        // ---- waves 0-1 finalize: reduce quarters, gate math, state update, writes ----
        if (wave < 2) {
            float g0 = red[0][0][p] + red[1][0][p] + red[2][0][p] + red[3][0][p] + bias[0];
            float g1 = red[0][1][p] + red[1][1][p] + red[2][1][p] + red[3][1][p] + bias[1];
            float g2 = red[0][2][p] + red[1][2][p] + red[2][2][p] + red[3][2][p] + bias[2];
            float g3 = red[0][3][p] + red[1][3][p] + red[2][3][p] + red[3][3][p] + bias[3];
            float ig = sigm(g0);
            float fg = sigm(g1);
            float gg = tanhf(g2);
            float og = sigm(g3);
            c = fg * c + ig * gg;
            float hv = og * tanhf(c);
            hbuf[(t & 1) * BH_ + b * H_ + j] = hv;          // publish h for next step
            enc[(size_t)(b * H_ + j) * T_ + t] = hv;        // encoded[b][j][t]
            if (t == T_ - 1) out[b * H_ + j] = hv;          // final hidden (1,B,H)
        }
        grid.sync();   // all blocks see hbuf[t&1] before step t+1 stages it
    }
}

extern "C" void kernel_launch(void* const* d_in, const int* in_sizes, int n_in,
                              void* d_out, int out_size, void* d_ws, size_t ws_size,
                              hipStream_t stream)
{
    (void)in_sizes; (void)n_in; (void)out_size; (void)ws_size;
    const float* x   = (const float*)d_in[0];
    const float* Wih = (const float*)d_in[1];
    const float* Whh = (const float*)d_in[2];
    const float* bih = (const float*)d_in[3];
    const float* bhh = (const float*)d_in[4];
    const float* h0  = (const float*)d_in[5];
    const float* c0  = (const float*)d_in[6];
    float* out  = (float*)d_out;
    float* hbuf = (float*)d_ws;   // 2 * B*H floats ping-pong = 256 KB

    void* args[] = { (void*)&x, (void*)&Wih, (void*)&Whh, (void*)&bih, (void*)&bhh,
                     (void*)&h0, (void*)&c0, (void*)&out, (void*)&hbuf };
    hipLaunchCooperativeKernel((void*)lstm_fused, dim3(256), dim3(512), args, 0, stream);
}